// Round 2
// baseline (423.413 us; speedup 1.0000x reference)
//
#include <hip/hip_runtime.h>
#include <cstdint>
#include <cstddef>

#define NB 16
#define NC 128
#define NH 128
#define NW 128
#define HM 1024
#define WM 1024
#define HW (NH*NW)
#define NHEADS 4
#define HDIM 32
// SIGMA2 = 2*0.3^2 = 0.18
#define INV_SIGMA2 5.555555555555555f

// ---- workspace layout (floats) ----
#define WS_M     0          // [B*2][128][128] downsampled masks (raw values)
#define WS_PART  524288     // [B*2][8][4] partial stats (msum, cnt, cy, cx)
#define WS_NUM   525312     // [B*2][128] pooled numerators
#define WS_NODES 529408     // [B*2][128] final node features
#define WS_WXY   533504     // [B*2][2][128] gaussian factors: [..][0][w]=wx, [..][1][h]=wy

__device__ __forceinline__ float dot4(float4 a, float4 b) {
    return a.x*b.x + a.y*b.y + a.z*b.z + a.w*b.w;
}

// ============ Kernel A: downsample masks + partial stats ============
// grid = B*2*8 (16 rows per block), block = 256
__global__ void kA(const float* __restrict__ masks, float* __restrict__ ws) {
    float* m_ds = ws + WS_M;
    float* part = ws + WS_PART;
    int blk = blockIdx.x;
    int b2 = blk >> 3;          // b*2 + n
    int chunk = blk & 7;
    int tid = threadIdx.x;
    int wcol = tid & 127;
    int rofs = tid >> 7;        // 0 or 1
    const float* mp = masks + (size_t)b2 * (HM * WM);
    float msum = 0.f, cnt = 0.f, cy = 0.f, cx = 0.f;
#pragma unroll
    for (int it = 0; it < 8; ++it) {
        int r = chunk * 16 + it * 2 + rofs;
        float v = mp[(size_t)(r * 8) * WM + wcol * 8];   // nearest: iy=h*8, ix=w*8
        m_ds[(size_t)b2 * HW + r * 128 + wcol] = v;
        msum += v;
        if (v > 0.5f) { cnt += 1.0f; cy += (float)r; cx += (float)wcol; }
    }
    // wave-level reduce (4 values), then cross-wave combine in LDS
    __shared__ float wred[4][4];
#pragma unroll
    for (int s = 32; s > 0; s >>= 1) {
        msum += __shfl_down(msum, s, 64);
        cnt  += __shfl_down(cnt,  s, 64);
        cy   += __shfl_down(cy,   s, 64);
        cx   += __shfl_down(cx,   s, 64);
    }
    if ((tid & 63) == 0) {
        int w = tid >> 6;
        wred[w][0] = msum; wred[w][1] = cnt; wred[w][2] = cy; wred[w][3] = cx;
    }
    __syncthreads();
    if (tid == 0) {
        float* p = part + (b2 * 8 + chunk) * 4;
        p[0] = wred[0][0] + wred[1][0] + wred[2][0] + wred[3][0];
        p[1] = wred[0][1] + wred[1][1] + wred[2][1] + wred[3][1];
        p[2] = wred[0][2] + wred[1][2] + wred[2][2] + wred[3][2];
        p[3] = wred[0][3] + wred[1][3] + wred[2][3] + wred[3][3];
    }
}

// ============ Kernel B: node pooling ============
// grid = B*C = 2048, block = 256
__global__ void kB(const float* __restrict__ x, const float* __restrict__ ws_full) {
    const float* ws_m = ws_full + WS_M;
    float* num = (float*)(ws_full + WS_NUM);
    int b = blockIdx.x >> 7, c = blockIdx.x & 127;
    int tid = threadIdx.x;
    const float4* xp = (const float4*)(x + ((size_t)b * NC + c) * HW);
    const float4* m0 = (const float4*)(ws_m + (size_t)(b * 2 + 0) * HW);
    const float4* m1 = (const float4*)(ws_m + (size_t)(b * 2 + 1) * HW);
    float a0 = 0.f, a1 = 0.f;
#pragma unroll
    for (int i = 0; i < 16; ++i) {
        int idx = i * 256 + tid;
        float4 xv = xp[idx];
        float4 v0 = m0[idx];
        float4 v1 = m1[idx];
        a0 += xv.x*v0.x + xv.y*v0.y + xv.z*v0.z + xv.w*v0.w;
        a1 += xv.x*v1.x + xv.y*v1.y + xv.z*v1.z + xv.w*v1.w;
    }
    __shared__ float wred[4][2];
#pragma unroll
    for (int s = 32; s > 0; s >>= 1) {
        a0 += __shfl_down(a0, s, 64);
        a1 += __shfl_down(a1, s, 64);
    }
    if ((tid & 63) == 0) { wred[tid >> 6][0] = a0; wred[tid >> 6][1] = a1; }
    __syncthreads();
    if (tid == 0) {
        num[(b * 2 + 0) * 128 + c] = wred[0][0] + wred[1][0] + wred[2][0] + wred[3][0];
        num[(b * 2 + 1) * 128 + c] = wred[0][1] + wred[1][1] + wred[2][1] + wred[3][1];
    }
}

// ============ Kernel C: tiny graph attention + FFN + gaussian factors ============
// grid = B = 16, block = 256.
// All matmuls: cooperative coalesced float4 loads + shuffle-reduce over the
// lanes sharing an output row. (Previous version: per-thread scalar strided
// loads -> latency-bound at 16 blocks; this was the dominant cost.)
__global__ void kC(const float* __restrict__ Wq, const float* __restrict__ bq,
                   const float* __restrict__ Wk, const float* __restrict__ bk,
                   const float* __restrict__ Wv, const float* __restrict__ bv,
                   const float* __restrict__ Wo, const float* __restrict__ bo,
                   const float* __restrict__ ln1w, const float* __restrict__ ln1b,
                   const float* __restrict__ W1, const float* __restrict__ b1,
                   const float* __restrict__ W2, const float* __restrict__ b2,
                   const float* __restrict__ ln2w, const float* __restrict__ ln2b,
                   float* __restrict__ ws) {
    int b = blockIdx.x;
    int tid = threadIdx.x;
    int c = tid & 127;
    int i = tid >> 7;   // node index for (i,c)-mapped phases

    const float* part = ws + WS_PART;
    const float* num  = ws + WS_NUM;
    float* nodesf = ws + WS_NODES;
    float* wxy    = ws + WS_WXY;

    __shared__ __align__(16) float s_n0[2][128];
    __shared__ __align__(16) float sQ[2][128], sK[2][128], sV[2][128];
    __shared__ __align__(16) float s_o[2][128];
    __shared__ __align__(16) float s_h1[2][128];
    __shared__ __align__(16) float s_n1[2][128];
    __shared__ __align__(16) float s_hid[2][256];
    __shared__ __align__(16) float s_h2[2][128];
    __shared__ float red[4];
    __shared__ float s_sc[16];
    __shared__ float s_at[NHEADS][2][2];
    __shared__ float s_px[2], s_py[2], s_den[2];

    // ---- stats -> pos, denom ----
    if (tid < 2) {
        int n = tid;
        float msum = 0.f, cnt = 0.f, cy = 0.f, cx = 0.f;
        const float* p = part + ((b * 2 + n) * 8) * 4;
        for (int ch = 0; ch < 8; ++ch) {
            msum += p[ch*4+0]; cnt += p[ch*4+1]; cy += p[ch*4+2]; cx += p[ch*4+3];
        }
        s_den[n] = msum + 1e-6f;
        float cm = fmaxf(cnt, 1.0f);
        s_px[n] = (cx / cm) / 64.0f - 1.0f;   // cx/W*2 - 1
        s_py[n] = (cy / cm) / 64.0f - 1.0f;
    }
    __syncthreads();

    s_n0[i][c] = num[(b * 2 + i) * 128 + c] / s_den[i];
    __syncthreads();

    // ---- QKV projections (coalesced cooperative) ----
    {
        float4 na0 = ((const float4*)s_n0[0])[tid & 31];   // n0[0][k0..k0+3], k0=(tid&31)*4
        float4 na1 = ((const float4*)s_n0[1])[tid & 31];
        const float4* Wq4 = (const float4*)Wq;
        const float4* Wk4 = (const float4*)Wk;
        const float4* Wv4 = (const float4*)Wv;
#pragma unroll 4
        for (int p = 0; p < 16; ++p) {
            int e4 = p * 256 + tid;
            float4 wq = Wq4[e4], wk = Wk4[e4], wv = Wv4[e4];
            int cc = e4 >> 5;                 // output row 0..127
            float q0 = dot4(wq, na0), q1 = dot4(wq, na1);
            float k0v = dot4(wk, na0), k1v = dot4(wk, na1);
            float v0 = dot4(wv, na0), v1 = dot4(wv, na1);
#pragma unroll
            for (int s = 16; s > 0; s >>= 1) {
                q0  += __shfl_down(q0,  s, 32); q1  += __shfl_down(q1,  s, 32);
                k0v += __shfl_down(k0v, s, 32); k1v += __shfl_down(k1v, s, 32);
                v0  += __shfl_down(v0,  s, 32); v1  += __shfl_down(v1,  s, 32);
            }
            if ((tid & 31) == 0) {
                float bQ = bq[cc], bK = bk[cc], bV = bv[cc];
                sQ[0][cc] = q0 + bQ;  sQ[1][cc] = q1 + bQ;
                sK[0][cc] = k0v + bK; sK[1][cc] = k1v + bK;
                sV[0][cc] = v0 + bV;  sV[1][cc] = v1 + bV;
            }
        }
    }
    __syncthreads();

    // ---- scores per (head, i, j) ----
    if (tid < 16) {
        int h = tid >> 2, ii = (tid >> 1) & 1, j = tid & 1;
        float s = 0.f;
        for (int d = 0; d < HDIM; ++d) s += sQ[ii][h*HDIM+d] * sK[j][h*HDIM+d];
        s *= 0.17677669529663687f;  // 1/sqrt(32)
        if (ii != j) {
            float dx = s_px[0] - s_px[1], dy = s_py[0] - s_py[1];
            float d2 = dx*dx + dy*dy;
            if (d2 > 0.f) s -= sqrtf(d2);
        }
        s_sc[tid] = s;
    }
    __syncthreads();

    if (tid < 8) {
        int h = tid >> 1, ii = tid & 1;
        float s0 = s_sc[h*4 + ii*2 + 0], s1 = s_sc[h*4 + ii*2 + 1];
        float mx = fmaxf(s0, s1);
        float e0 = expf(s0 - mx), e1 = expf(s1 - mx);
        float inv = 1.0f / (e0 + e1);
        s_at[h][ii][0] = e0 * inv;
        s_at[h][ii][1] = e1 * inv;
    }
    __syncthreads();

    {
        int h = c >> 5;
        s_o[i][c] = s_at[h][i][0] * sV[0][c] + s_at[h][i][1] * sV[1][c];
    }
    __syncthreads();

    // ---- Wo projection + residual ----
    {
        float4 oa0 = ((const float4*)s_o[0])[tid & 31];
        float4 oa1 = ((const float4*)s_o[1])[tid & 31];
        const float4* Wo4 = (const float4*)Wo;
#pragma unroll 4
        for (int p = 0; p < 16; ++p) {
            int e4 = p * 256 + tid;
            float4 w = Wo4[e4];
            int cc = e4 >> 5;
            float v0 = dot4(w, oa0), v1 = dot4(w, oa1);
#pragma unroll
            for (int s = 16; s > 0; s >>= 1) {
                v0 += __shfl_down(v0, s, 32); v1 += __shfl_down(v1, s, 32);
            }
            if ((tid & 31) == 0) {
                float bb = bo[cc];
                s_h1[0][cc] = v0 + bb + s_n0[0][cc];
                s_h1[1][cc] = v1 + bb + s_n0[1][cc];
            }
        }
    }
    __syncthreads();

    // ---- LN1 (wave shuffle + 4-entry LDS combine); rows: i=tid>>7 owned by waves 2i,2i+1 ----
    {
        float h = s_h1[i][c];
        float v = h;
#pragma unroll
        for (int s = 32; s > 0; s >>= 1) v += __shfl_down(v, s, 64);
        if ((tid & 63) == 0) red[tid >> 6] = v;
        __syncthreads();
        float mean = (red[i*2] + red[i*2+1]) * (1.0f / 128.0f);
        float d = h - mean;
        float v2 = d * d;
        __syncthreads();   // protect red before reuse
#pragma unroll
        for (int s = 32; s > 0; s >>= 1) v2 += __shfl_down(v2, s, 64);
        if ((tid & 63) == 0) red[tid >> 6] = v2;
        __syncthreads();
        float var = (red[i*2] + red[i*2+1]) * (1.0f / 128.0f);
        s_n1[i][c] = d * rsqrtf(var + 1e-5f) * ln1w[c] + ln1b[c];
    }
    __syncthreads();

    // ---- FFN layer 1: W1 (256x128), ReLU ----
    {
        float4 na0 = ((const float4*)s_n1[0])[tid & 31];
        float4 na1 = ((const float4*)s_n1[1])[tid & 31];
        const float4* W1_4 = (const float4*)W1;
#pragma unroll 4
        for (int p = 0; p < 32; ++p) {
            int e4 = p * 256 + tid;
            float4 w = W1_4[e4];
            int j = e4 >> 5;                  // hidden idx 0..255
            float v0 = dot4(w, na0), v1 = dot4(w, na1);
#pragma unroll
            for (int s = 16; s > 0; s >>= 1) {
                v0 += __shfl_down(v0, s, 32); v1 += __shfl_down(v1, s, 32);
            }
            if ((tid & 31) == 0) {
                float bb = b1[j];
                s_hid[0][j] = fmaxf(v0 + bb, 0.0f);
                s_hid[1][j] = fmaxf(v1 + bb, 0.0f);
            }
        }
    }
    __syncthreads();

    // ---- FFN layer 2: W2 (128x256) + residual; rows of length 256 -> full-wave reduce ----
    {
        float4 ha0 = ((const float4*)s_hid[0])[tid & 63];  // k0=(tid&63)*4
        float4 ha1 = ((const float4*)s_hid[1])[tid & 63];
        const float4* W2_4 = (const float4*)W2;
#pragma unroll 4
        for (int p = 0; p < 32; ++p) {
            int e4 = p * 256 + tid;
            float4 w = W2_4[e4];
            int cc = e4 >> 6;                 // output row 0..127
            float v0 = dot4(w, ha0), v1 = dot4(w, ha1);
#pragma unroll
            for (int s = 32; s > 0; s >>= 1) {
                v0 += __shfl_down(v0, s, 64); v1 += __shfl_down(v1, s, 64);
            }
            if ((tid & 63) == 0) {
                float bb = b2[cc];
                s_h2[0][cc] = v0 + bb + s_n1[0][cc];
                s_h2[1][cc] = v1 + bb + s_n1[1][cc];
            }
        }
    }
    __syncthreads();

    // ---- LN2 -> final nodes ----
    {
        float h = s_h2[i][c];
        float v = h;
#pragma unroll
        for (int s = 32; s > 0; s >>= 1) v += __shfl_down(v, s, 64);
        if ((tid & 63) == 0) red[tid >> 6] = v;
        __syncthreads();
        float mean = (red[i*2] + red[i*2+1]) * (1.0f / 128.0f);
        float d = h - mean;
        float v2 = d * d;
        __syncthreads();
#pragma unroll
        for (int s = 32; s > 0; s >>= 1) v2 += __shfl_down(v2, s, 64);
        if ((tid & 63) == 0) red[tid >> 6] = v2;
        __syncthreads();
        float var = (red[i*2] + red[i*2+1]) * (1.0f / 128.0f);
        nodesf[(b * 2 + i) * 128 + c] = d * rsqrtf(var + 1e-5f) * ln2w[c] + ln2b[c];
    }

    // ---- separable gaussian factors (linspace(-1,1,128)) ----
    {
        float g = (float)c * (2.0f / 127.0f) - 1.0f;
        float dx = g - s_px[i];
        float dy = g - s_py[i];
        wxy[((b*2+i)*2 + 0) * 128 + c] = expf(-dx * dx * INV_SIGMA2);
        wxy[((b*2+i)*2 + 1) * 128 + c] = expf(-dy * dy * INV_SIGMA2);
    }
}

// ============ Kernel D: gaussian broadcast + residual ============
// grid = B*C = 2048, block = 256
__global__ void kD(const float* __restrict__ x, const float* __restrict__ ws,
                   float* __restrict__ out) {
    const float* nodesf = ws + WS_NODES;
    const float* wxy    = ws + WS_WXY;
    int b = blockIdx.x >> 7, c = blockIdx.x & 127;
    int tid = threadIdx.x;
    __shared__ float4 swx0[32], swx1[32];
    __shared__ float swy0[128], swy1[128];
    if (tid < 128) {
        swy0[tid] = wxy[((b*2+0)*2 + 1) * 128 + tid];
        swy1[tid] = wxy[((b*2+1)*2 + 1) * 128 + tid];
    } else {
        int t = tid - 128;
        if (t < 32)      swx0[t]      = ((const float4*)(wxy + ((b*2+0)*2 + 0) * 128))[t];
        else if (t < 64) swx1[t - 32] = ((const float4*)(wxy + ((b*2+1)*2 + 0) * 128))[t - 32];
    }
    float n0 = nodesf[(b * 2 + 0) * 128 + c];
    float n1 = nodesf[(b * 2 + 1) * 128 + c];
    __syncthreads();
    const float4* xp = (const float4*)(x   + ((size_t)b * NC + c) * HW);
    float4*       op = (float4*)      (out + ((size_t)b * NC + c) * HW);
#pragma unroll
    for (int it = 0; it < 16; ++it) {
        int p4 = it * 256 + tid;
        int h = p4 >> 5;       // 32 float4 per row
        int w4 = p4 & 31;
        float a0 = n0 * swy0[h];
        float a1 = n1 * swy1[h];
        float4 xv = xp[p4];
        float4 wx0 = swx0[w4], wx1 = swx1[w4];
        float4 r;
        r.x = xv.x + a0 * wx0.x + a1 * wx1.x;
        r.y = xv.y + a0 * wx0.y + a1 * wx1.y;
        r.z = xv.z + a0 * wx0.z + a1 * wx1.z;
        r.w = xv.w + a0 * wx0.w + a1 * wx1.w;
        op[p4] = r;
    }
}

extern "C" void kernel_launch(void* const* d_in, const int* in_sizes, int n_in,
                              void* d_out, int out_size, void* d_ws, size_t ws_size,
                              hipStream_t stream) {
    const float* x     = (const float*)d_in[0];
    const float* masks = (const float*)d_in[1];
    const float* Wq    = (const float*)d_in[2];
    const float* bq    = (const float*)d_in[3];
    const float* Wk    = (const float*)d_in[4];
    const float* bk    = (const float*)d_in[5];
    const float* Wv    = (const float*)d_in[6];
    const float* bv    = (const float*)d_in[7];
    const float* Wo    = (const float*)d_in[8];
    const float* bo    = (const float*)d_in[9];
    const float* ln1w  = (const float*)d_in[10];
    const float* ln1b  = (const float*)d_in[11];
    const float* W1    = (const float*)d_in[12];
    const float* b1    = (const float*)d_in[13];
    const float* W2    = (const float*)d_in[14];
    const float* b2    = (const float*)d_in[15];
    const float* ln2w  = (const float*)d_in[16];
    const float* ln2b  = (const float*)d_in[17];
    float* out = (float*)d_out;
    float* ws  = (float*)d_ws;

    hipLaunchKernelGGL(kA, dim3(NB * 2 * 8), dim3(256), 0, stream, masks, ws);
    hipLaunchKernelGGL(kB, dim3(NB * NC), dim3(256), 0, stream, x, ws);
    hipLaunchKernelGGL(kC, dim3(NB), dim3(256), 0, stream,
                       Wq, bq, Wk, bk, Wv, bv, Wo, bo, ln1w, ln1b,
                       W1, b1, W2, b2, ln2w, ln2b, ws);
    hipLaunchKernelGGL(kD, dim3(NB * NC), dim3(256), 0, stream, x, ws, out);
}

// Round 3
// 364.307 us; speedup vs baseline: 1.1622x; 1.1622x over previous
//
#include <hip/hip_runtime.h>
#include <cstdint>
#include <cstddef>

#define NB 16
#define NC 128
#define NH 128
#define NW 128
#define HM 1024
#define WM 1024
#define HW (NH*NW)
#define NHEADS 4
#define HDIM 32
// SIGMA2 = 2*0.3^2 = 0.18
#define INV_SIGMA2 5.555555555555555f

// ---- workspace layout (floats) ----
#define WS_M     0          // [B*2][128][128] downsampled masks (raw values)
#define WS_PART  524288     // [B*2][8][4] partial stats (msum, cnt, cy, cx)
#define WS_NUM   525312     // [B*2][128] pooled numerators
#define WS_NODES 529408     // [B*2][128] final node features
#define WS_WXY   533504     // [B*2][2][128] gaussian factors: [..][0][w]=wx, [..][1][h]=wy

__device__ __forceinline__ float dot4(float4 a, float4 b) {
    return a.x*b.x + a.y*b.y + a.z*b.z + a.w*b.w;
}

// ============ Kernel A: downsample masks + partial stats ============
// grid = B*2*8 (16 rows per block), block = 256
__global__ void kA(const float* __restrict__ masks, float* __restrict__ ws) {
    float* m_ds = ws + WS_M;
    float* part = ws + WS_PART;
    int blk = blockIdx.x;
    int b2 = blk >> 3;          // b*2 + n
    int chunk = blk & 7;
    int tid = threadIdx.x;
    int wcol = tid & 127;
    int rofs = tid >> 7;        // 0 or 1
    const float* mp = masks + (size_t)b2 * (HM * WM);
    float msum = 0.f, cnt = 0.f, cy = 0.f, cx = 0.f;
#pragma unroll
    for (int it = 0; it < 8; ++it) {
        int r = chunk * 16 + it * 2 + rofs;
        float v = mp[(size_t)(r * 8) * WM + wcol * 8];   // nearest: iy=h*8, ix=w*8
        m_ds[(size_t)b2 * HW + r * 128 + wcol] = v;
        msum += v;
        if (v > 0.5f) { cnt += 1.0f; cy += (float)r; cx += (float)wcol; }
    }
    __shared__ float wred[4][4];
#pragma unroll
    for (int s = 32; s > 0; s >>= 1) {
        msum += __shfl_down(msum, s, 64);
        cnt  += __shfl_down(cnt,  s, 64);
        cy   += __shfl_down(cy,   s, 64);
        cx   += __shfl_down(cx,   s, 64);
    }
    if ((tid & 63) == 0) {
        int w = tid >> 6;
        wred[w][0] = msum; wred[w][1] = cnt; wred[w][2] = cy; wred[w][3] = cx;
    }
    __syncthreads();
    if (tid == 0) {
        float* p = part + (b2 * 8 + chunk) * 4;
        p[0] = wred[0][0] + wred[1][0] + wred[2][0] + wred[3][0];
        p[1] = wred[0][1] + wred[1][1] + wred[2][1] + wred[3][1];
        p[2] = wred[0][2] + wred[1][2] + wred[2][2] + wred[3][2];
        p[3] = wred[0][3] + wred[1][3] + wred[2][3] + wred[3][3];
    }
}

// ============ Kernel B: node pooling ============
// grid = B*C = 2048, block = 256
__global__ void kB(const float* __restrict__ x, const float* __restrict__ ws_full) {
    const float* ws_m = ws_full + WS_M;
    float* num = (float*)(ws_full + WS_NUM);
    int b = blockIdx.x >> 7, c = blockIdx.x & 127;
    int tid = threadIdx.x;
    const float4* xp = (const float4*)(x + ((size_t)b * NC + c) * HW);
    const float4* m0 = (const float4*)(ws_m + (size_t)(b * 2 + 0) * HW);
    const float4* m1 = (const float4*)(ws_m + (size_t)(b * 2 + 1) * HW);
    float a0 = 0.f, a1 = 0.f;
#pragma unroll
    for (int i = 0; i < 16; ++i) {
        int idx = i * 256 + tid;
        float4 xv = xp[idx];
        float4 v0 = m0[idx];
        float4 v1 = m1[idx];
        a0 += xv.x*v0.x + xv.y*v0.y + xv.z*v0.z + xv.w*v0.w;
        a1 += xv.x*v1.x + xv.y*v1.y + xv.z*v1.z + xv.w*v1.w;
    }
    __shared__ float wred[4][2];
#pragma unroll
    for (int s = 32; s > 0; s >>= 1) {
        a0 += __shfl_down(a0, s, 64);
        a1 += __shfl_down(a1, s, 64);
    }
    if ((tid & 63) == 0) { wred[tid >> 6][0] = a0; wred[tid >> 6][1] = a1; }
    __syncthreads();
    if (tid == 0) {
        num[(b * 2 + 0) * 128 + c] = wred[0][0] + wred[1][0] + wred[2][0] + wred[3][0];
        num[(b * 2 + 1) * 128 + c] = wred[0][1] + wred[1][1] + wred[2][1] + wred[3][1];
    }
}

// ============ Kernel C: tiny graph attention + FFN + gaussian factors ============
// grid = B = 16, block = 256, one block per batch.
// Latency-bound kernel (64 waves on 256 CUs): the design rule is MAXIMUM
// independent loads in flight, issued as early as possible. Each thread owns a
// half-row (64 floats = 16 float4) of each 128-col weight matrix, loaded into a
// register array in one batch; next-stage weights are issued before the
// current stage's LDS/shuffle work so their latency hides under it.
__global__ void __launch_bounds__(256, 1)
kC(const float* __restrict__ Wq, const float* __restrict__ bq,
   const float* __restrict__ Wk, const float* __restrict__ bk,
   const float* __restrict__ Wv, const float* __restrict__ bv,
   const float* __restrict__ Wo, const float* __restrict__ bo,
   const float* __restrict__ ln1w, const float* __restrict__ ln1b,
   const float* __restrict__ W1, const float* __restrict__ b1,
   const float* __restrict__ W2, const float* __restrict__ b2,
   const float* __restrict__ ln2w, const float* __restrict__ ln2b,
   float* __restrict__ ws) {
    int b = blockIdx.x;
    int tid = threadIdx.x;
    int c = tid & 127;
    int i = tid >> 7;     // node index for (i,c)-mapped phases
    int r = tid >> 1;     // output row 0..127 for pair-mapped matmuls
    int hv = tid & 1;     // which half of the k-dimension this thread owns

    const float* part = ws + WS_PART;
    const float* num  = ws + WS_NUM;
    float* nodesf = ws + WS_NODES;
    float* wxy    = ws + WS_WXY;

    __shared__ __align__(16) float s_n0[2][128];
    __shared__ __align__(16) float sQ[2][128], sK[2][128], sV[2][128];
    __shared__ __align__(16) float s_o[2][128];
    __shared__ __align__(16) float s_h1[2][128];
    __shared__ __align__(16) float s_n1[2][128];
    __shared__ __align__(16) float s_hid[2][256];
    __shared__ __align__(16) float s_h2[2][128];
    __shared__ float red[4];
    __shared__ float s_sc[16];
    __shared__ float s_at[NHEADS][2][2];
    __shared__ float s_px[2], s_py[2], s_den[2];

    // ---- issue QKV weight loads immediately (independent of everything) ----
    const float4* Wq4 = (const float4*)Wq + (r << 5) + (hv << 4);
    const float4* Wk4 = (const float4*)Wk + (r << 5) + (hv << 4);
    const float4* Wv4 = (const float4*)Wv + (r << 5) + (hv << 4);
    float4 wq[16], wk[16], wv[16];
#pragma unroll
    for (int k = 0; k < 16; ++k) wq[k] = Wq4[k];
#pragma unroll
    for (int k = 0; k < 16; ++k) wk[k] = Wk4[k];
#pragma unroll
    for (int k = 0; k < 16; ++k) wv[k] = Wv4[k];
    // scalar params (all independent) — issue now too
    float biasq = bq[r], biask = bk[r], biasv = bv[r], biaso = bo[r];
    float bias1 = b1[tid];              // FFN1: one thread per hidden unit
    float bias2 = b2[r];
    float l1w = ln1w[c], l1b = ln1b[c], l2w = ln2w[c], l2b = ln2b[c];

    // ---- stats -> pos, denom ----
    if (tid < 2) {
        int n = tid;
        float msum = 0.f, cnt = 0.f, cy = 0.f, cx = 0.f;
        const float* p = part + ((b * 2 + n) * 8) * 4;
        for (int ch = 0; ch < 8; ++ch) {
            msum += p[ch*4+0]; cnt += p[ch*4+1]; cy += p[ch*4+2]; cx += p[ch*4+3];
        }
        s_den[n] = msum + 1e-6f;
        float cm = fmaxf(cnt, 1.0f);
        s_px[n] = (cx / cm) / 64.0f - 1.0f;   // cx/W*2 - 1
        s_py[n] = (cy / cm) / 64.0f - 1.0f;
    }
    __syncthreads();

    s_n0[i][c] = num[(b * 2 + i) * 128 + c] / s_den[i];
    __syncthreads();

    // ---- QKV: each thread: half-row dot for both nodes; pair-combine ----
    {
        const float4* a0 = (const float4*)&s_n0[0][0] + (hv << 4);
        const float4* a1 = (const float4*)&s_n0[1][0] + (hv << 4);
        float q0 = 0.f, q1 = 0.f, k0v = 0.f, k1v = 0.f, v0 = 0.f, v1 = 0.f;
#pragma unroll
        for (int k = 0; k < 16; ++k) {
            float4 x0 = a0[k], x1 = a1[k];
            q0  += dot4(wq[k], x0); q1  += dot4(wq[k], x1);
            k0v += dot4(wk[k], x0); k1v += dot4(wk[k], x1);
            v0  += dot4(wv[k], x0); v1  += dot4(wv[k], x1);
        }
        q0  += __shfl_xor(q0,  1); q1  += __shfl_xor(q1,  1);
        k0v += __shfl_xor(k0v, 1); k1v += __shfl_xor(k1v, 1);
        v0  += __shfl_xor(v0,  1); v1  += __shfl_xor(v1,  1);
        if (hv == 0) {
            sQ[0][r] = q0 + biasq;  sQ[1][r] = q1 + biasq;
            sK[0][r] = k0v + biask; sK[1][r] = k1v + biask;
            sV[0][r] = v0 + biasv;  sV[1][r] = v1 + biasv;
        }
    }

    // ---- prefetch Wo + W1 (hide under attention / LN1) ----
    const float4* Wo4 = (const float4*)Wo + (r << 5) + (hv << 4);
    float4 wo[16];
#pragma unroll
    for (int k = 0; k < 16; ++k) wo[k] = Wo4[k];
    const float4* W1_4 = (const float4*)W1 + (tid << 5);   // full row per thread
    float4 w1[32];
#pragma unroll
    for (int k = 0; k < 32; ++k) w1[k] = W1_4[k];

    __syncthreads();

    // ---- scores per (head, i, j) ----
    if (tid < 16) {
        int h = tid >> 2, ii = (tid >> 1) & 1, j = tid & 1;
        float s = 0.f;
        for (int d = 0; d < HDIM; ++d) s += sQ[ii][h*HDIM+d] * sK[j][h*HDIM+d];
        s *= 0.17677669529663687f;  // 1/sqrt(32)
        if (ii != j) {
            float dx = s_px[0] - s_px[1], dy = s_py[0] - s_py[1];
            float d2 = dx*dx + dy*dy;
            if (d2 > 0.f) s -= sqrtf(d2);
        }
        s_sc[tid] = s;
    }
    __syncthreads();

    if (tid < 8) {
        int h = tid >> 1, ii = tid & 1;
        float s0 = s_sc[h*4 + ii*2 + 0], s1 = s_sc[h*4 + ii*2 + 1];
        float mx = fmaxf(s0, s1);
        float e0 = expf(s0 - mx), e1 = expf(s1 - mx);
        float inv = 1.0f / (e0 + e1);
        s_at[h][ii][0] = e0 * inv;
        s_at[h][ii][1] = e1 * inv;
    }
    __syncthreads();

    {
        int h = c >> 5;
        s_o[i][c] = s_at[h][i][0] * sV[0][c] + s_at[h][i][1] * sV[1][c];
    }
    __syncthreads();

    // ---- Wo projection + residual ----
    {
        const float4* a0 = (const float4*)&s_o[0][0] + (hv << 4);
        const float4* a1 = (const float4*)&s_o[1][0] + (hv << 4);
        float v0 = 0.f, v1 = 0.f;
#pragma unroll
        for (int k = 0; k < 16; ++k) {
            v0 += dot4(wo[k], a0[k]);
            v1 += dot4(wo[k], a1[k]);
        }
        v0 += __shfl_xor(v0, 1);
        v1 += __shfl_xor(v1, 1);
        if (hv == 0) {
            s_h1[0][r] = v0 + biaso + s_n0[0][r];
            s_h1[1][r] = v1 + biaso + s_n0[1][r];
        }
    }
    __syncthreads();

    // ---- LN1 (wave shuffle + 4-entry LDS combine) ----
    {
        float h = s_h1[i][c];
        float v = h;
#pragma unroll
        for (int s = 32; s > 0; s >>= 1) v += __shfl_down(v, s, 64);
        if ((tid & 63) == 0) red[tid >> 6] = v;
        __syncthreads();
        float mean = (red[i*2] + red[i*2+1]) * (1.0f / 128.0f);
        float d = h - mean;
        float v2 = d * d;
        __syncthreads();
#pragma unroll
        for (int s = 32; s > 0; s >>= 1) v2 += __shfl_down(v2, s, 64);
        if ((tid & 63) == 0) red[tid >> 6] = v2;
        __syncthreads();
        float var = (red[i*2] + red[i*2+1]) * (1.0f / 128.0f);
        s_n1[i][c] = d * rsqrtf(var + 1e-5f) * l1w + l1b;
    }
    __syncthreads();

    // ---- FFN layer 1: thread owns hidden unit j = tid (full row of W1) ----
    {
        const float4* a0 = (const float4*)&s_n1[0][0];
        const float4* a1 = (const float4*)&s_n1[1][0];
        float v0 = 0.f, v1 = 0.f;
#pragma unroll
        for (int k = 0; k < 32; ++k) {
            v0 += dot4(w1[k], a0[k]);
            v1 += dot4(w1[k], a1[k]);
        }
        s_hid[0][tid] = fmaxf(v0 + bias1, 0.0f);
        s_hid[1][tid] = fmaxf(v1 + bias1, 0.0f);
    }

    // ---- prefetch W2 (hide under the sync + FFN2 front) ----
    const float4* W2_4 = (const float4*)W2 + (r << 6) + (hv << 5);  // half of 256-float row
    float4 w2[32];
#pragma unroll
    for (int k = 0; k < 32; ++k) w2[k] = W2_4[k];

    __syncthreads();

    // ---- FFN layer 2 + residual: pair-mapped over 256-float rows ----
    {
        const float4* a0 = (const float4*)&s_hid[0][0] + (hv << 5);
        const float4* a1 = (const float4*)&s_hid[1][0] + (hv << 5);
        float v0 = 0.f, v1 = 0.f;
#pragma unroll
        for (int k = 0; k < 32; ++k) {
            v0 += dot4(w2[k], a0[k]);
            v1 += dot4(w2[k], a1[k]);
        }
        v0 += __shfl_xor(v0, 1);
        v1 += __shfl_xor(v1, 1);
        if (hv == 0) {
            s_h2[0][r] = v0 + bias2 + s_n1[0][r];
            s_h2[1][r] = v1 + bias2 + s_n1[1][r];
        }
    }
    __syncthreads();

    // ---- LN2 -> final nodes ----
    {
        float h = s_h2[i][c];
        float v = h;
#pragma unroll
        for (int s = 32; s > 0; s >>= 1) v += __shfl_down(v, s, 64);
        if ((tid & 63) == 0) red[tid >> 6] = v;
        __syncthreads();
        float mean = (red[i*2] + red[i*2+1]) * (1.0f / 128.0f);
        float d = h - mean;
        float v2 = d * d;
        __syncthreads();
#pragma unroll
        for (int s = 32; s > 0; s >>= 1) v2 += __shfl_down(v2, s, 64);
        if ((tid & 63) == 0) red[tid >> 6] = v2;
        __syncthreads();
        float var = (red[i*2] + red[i*2+1]) * (1.0f / 128.0f);
        nodesf[(b * 2 + i) * 128 + c] = d * rsqrtf(var + 1e-5f) * l2w + l2b;
    }

    // ---- separable gaussian factors (linspace(-1,1,128)) ----
    {
        float g = (float)c * (2.0f / 127.0f) - 1.0f;
        float dx = g - s_px[i];
        float dy = g - s_py[i];
        wxy[((b*2+i)*2 + 0) * 128 + c] = expf(-dx * dx * INV_SIGMA2);
        wxy[((b*2+i)*2 + 1) * 128 + c] = expf(-dy * dy * INV_SIGMA2);
    }
}

// ============ Kernel D: gaussian broadcast + residual ============
// grid = B*C = 2048, block = 256
__global__ void kD(const float* __restrict__ x, const float* __restrict__ ws,
                   float* __restrict__ out) {
    const float* nodesf = ws + WS_NODES;
    const float* wxy    = ws + WS_WXY;
    int b = blockIdx.x >> 7, c = blockIdx.x & 127;
    int tid = threadIdx.x;
    __shared__ float4 swx0[32], swx1[32];
    __shared__ float swy0[128], swy1[128];
    if (tid < 128) {
        swy0[tid] = wxy[((b*2+0)*2 + 1) * 128 + tid];
        swy1[tid] = wxy[((b*2+1)*2 + 1) * 128 + tid];
    } else {
        int t = tid - 128;
        if (t < 32)      swx0[t]      = ((const float4*)(wxy + ((b*2+0)*2 + 0) * 128))[t];
        else if (t < 64) swx1[t - 32] = ((const float4*)(wxy + ((b*2+1)*2 + 0) * 128))[t - 32];
    }
    float n0 = nodesf[(b * 2 + 0) * 128 + c];
    float n1 = nodesf[(b * 2 + 1) * 128 + c];
    __syncthreads();
    const float4* xp = (const float4*)(x   + ((size_t)b * NC + c) * HW);
    float4*       op = (float4*)      (out + ((size_t)b * NC + c) * HW);
#pragma unroll
    for (int it = 0; it < 16; ++it) {
        int p4 = it * 256 + tid;
        int h = p4 >> 5;       // 32 float4 per row
        int w4 = p4 & 31;
        float a0 = n0 * swy0[h];
        float a1 = n1 * swy1[h];
        float4 xv = xp[p4];
        float4 wx0 = swx0[w4], wx1 = swx1[w4];
        float4 r;
        r.x = xv.x + a0 * wx0.x + a1 * wx1.x;
        r.y = xv.y + a0 * wx0.y + a1 * wx1.y;
        r.z = xv.z + a0 * wx0.z + a1 * wx1.z;
        r.w = xv.w + a0 * wx0.w + a1 * wx1.w;
        op[p4] = r;
    }
}

extern "C" void kernel_launch(void* const* d_in, const int* in_sizes, int n_in,
                              void* d_out, int out_size, void* d_ws, size_t ws_size,
                              hipStream_t stream) {
    const float* x     = (const float*)d_in[0];
    const float* masks = (const float*)d_in[1];
    const float* Wq    = (const float*)d_in[2];
    const float* bq    = (const float*)d_in[3];
    const float* Wk    = (const float*)d_in[4];
    const float* bk    = (const float*)d_in[5];
    const float* Wv    = (const float*)d_in[6];
    const float* bv    = (const float*)d_in[7];
    const float* Wo    = (const float*)d_in[8];
    const float* bo    = (const float*)d_in[9];
    const float* ln1w  = (const float*)d_in[10];
    const float* ln1b  = (const float*)d_in[11];
    const float* W1    = (const float*)d_in[12];
    const float* b1    = (const float*)d_in[13];
    const float* W2    = (const float*)d_in[14];
    const float* b2    = (const float*)d_in[15];
    const float* ln2w  = (const float*)d_in[16];
    const float* ln2b  = (const float*)d_in[17];
    float* out = (float*)d_out;
    float* ws  = (float*)d_ws;

    hipLaunchKernelGGL(kA, dim3(NB * 2 * 8), dim3(256), 0, stream, masks, ws);
    hipLaunchKernelGGL(kB, dim3(NB * NC), dim3(256), 0, stream, x, ws);
    hipLaunchKernelGGL(kC, dim3(NB), dim3(256), 0, stream,
                       Wq, bq, Wk, bk, Wv, bv, Wo, bo, ln1w, ln1b,
                       W1, b1, W2, b2, ln2w, ln2b, ws);
    hipLaunchKernelGGL(kD, dim3(NB * NC), dim3(256), 0, stream, x, ws, out);
}